// Round 11
// baseline (142.719 us; speedup 1.0000x reference)
//
#include <hip/hip_runtime.h>
#include <stdint.h>

// Problem constants (fixed by setup_inputs)
#define TOKENS 64
#define IN_F   4096
#define OUT_F  11008
#define RANK   16
#define GS     128
#define NG     32
#define ZCOLS  (OUT_F / 8)
#define LORA_SCALE 2.0f
#define PROW 36               // padded LDS partial row stride (floats)

using short8  = __attribute__((ext_vector_type(8))) short;
using float4v = __attribute__((ext_vector_type(4))) float;

// round-to-nearest-even fp32 -> bf16 bits; also returns the rounded-back fp32
static __device__ inline uint16_t f2bf(float f, float* back) {
    uint32_t u = __float_as_uint(f);
    uint32_t r = (u + 0x7FFFu + ((u >> 16) & 1u)) >> 16;
    *back = __uint_as_float(r << 16);
    return (uint16_t)r;
}

// ---------------------------------------------------------------------------
// K1: per token t (64 blocks):
//   xf (MFMA-fragment order) = bf16(x)  — xf4[(mt*128 + kchunk)*64 + quad*16 + n]
//   xsumT[g][t] = sum over group g of bf16-rounded x   (GPTQ zero fold)
//   midT[j][t]  = sum_k x[t][k] * lora_A[j][k]         (fp32 LoRA mid)
// ---------------------------------------------------------------------------
__global__ __launch_bounds__(256) void prep_kernel(
        const float* __restrict__ x,
        const float* __restrict__ loraA,
        uint4* __restrict__ xf4,
        float* __restrict__ xsumT,
        float* __restrict__ midT) {
    __shared__ float redg[256];
    __shared__ float redm[4][16];
    const int t    = blockIdx.x;
    const int tid  = threadIdx.x;
    const int lane = tid & 63;
    const int wv   = tid >> 6;

    float4 xv[4];
    const float4* xp = (const float4*)(x + (size_t)t * IN_F + tid * 16);
    #pragma unroll
    for (int i = 0; i < 4; ++i) xv[i] = xp[i];

    union { uint16_t u[16]; uint4 q[2]; } ob;
    float s = 0.f;
    #pragma unroll
    for (int i = 0; i < 4; ++i) {
        float b;
        ob.u[i * 4 + 0] = f2bf(xv[i].x, &b); s += b;
        ob.u[i * 4 + 1] = f2bf(xv[i].y, &b); s += b;
        ob.u[i * 4 + 2] = f2bf(xv[i].z, &b); s += b;
        ob.u[i * 4 + 3] = f2bf(xv[i].w, &b); s += b;
    }
    // scatter into fragment order
    {
        const int mm = t >> 4, nn = t & 15;
        const int kchunk = tid >> 1;
        #pragma unroll
        for (int i = 0; i < 2; ++i) {
            const int qd = (tid * 2 + i) & 3;
            xf4[(size_t)((mm * 128 + kchunk) * 64 + qd * 16 + nn)] = ob.q[i];
        }
    }
    redg[tid] = s;

    // LoRA mid partials
    float pj[16];
    #pragma unroll
    for (int j = 0; j < 16; ++j) {
        const float4* ap = (const float4*)(loraA + (size_t)j * IN_F + tid * 16);
        float ps = 0.f;
        #pragma unroll
        for (int i = 0; i < 4; ++i) {
            float4 a = ap[i];
            ps += a.x * xv[i].x + a.y * xv[i].y + a.z * xv[i].z + a.w * xv[i].w;
        }
        pj[j] = ps;
    }
    #pragma unroll
    for (int j = 0; j < 16; ++j) {
        #pragma unroll
        for (int off = 32; off; off >>= 1) pj[j] += __shfl_down(pj[j], off);
    }
    if (lane == 0) {
        #pragma unroll
        for (int j = 0; j < 16; ++j) redm[wv][j] = pj[j];
    }
    __syncthreads();
    if (tid < NG) {
        float g = 0.f;
        #pragma unroll
        for (int i = 0; i < 8; ++i) g += redg[tid * 8 + i];
        xsumT[tid * TOKENS + t] = g;
    }
    if (tid < 16)
        midT[tid * TOKENS + t] = redm[0][tid] + redm[1][tid] + redm[2][tid] + redm[3][tid];
}

// ---------------------------------------------------------------------------
// K2: two-phase GPTQ-dequant GEMM + in-LDS split-K reduce + LoRA epilogue.
// Phase 1: bulk-stream the block's whole qweight slice (512 rows x 32 cols =
//   64 KB) into LDS (uint4 loads + ds_write_b128) and prefetch scales/qzeros
//   (cold HBM) into registers; ONE drain at the barrier -> full stream BW.
// Phase 2: barrier-free K-loop. vmcnt queue holds ONLY L2-hot loads (xf
//   A-fragments depth-3 ring + xsumT); B comes from LDS via ds_read_b32
//   (lgkmcnt — independent of vmcnt, so slow/fast latencies never mix).
// Block 512 = 8 waves = (mh 0/1) x (kseg 0..3); wave = 2 M-tiles x 32 cols
// x 8 groups (each dequanted word feeds 2 MFMAs). LDS partials (PROW=36,
// conflict-free) aliased over the dead B region; 3 barriers total.
// ---------------------------------------------------------------------------
__global__ __launch_bounds__(512, 4) void main_kernel(
        const uint32_t* __restrict__ qw,
        const uint32_t* __restrict__ qz,
        const float* __restrict__ scales,
        const uint4* __restrict__ xf4,
        const float* __restrict__ xsumT,
        const float* __restrict__ midT,
        const float* __restrict__ loraB,
        float* __restrict__ out) {
    __shared__ uint32_t smem[16384];   // 64 KB: B slice; later aliased by partials

    const int tid  = threadIdx.x;
    const int w    = tid >> 6;
    const int lane = tid & 63;
    const int n    = lane & 15;
    const int quad = lane >> 4;
    const int mh   = w >> 2;               // token half
    const int kseg = w & 3;                // 8-group K segment
    const int col0 = blockIdx.x * 32;
    const int g0   = kseg * 8;

    // ---------------- phase 1: bulk staging ----------------
    uint4 stg[8];
    #pragma unroll
    for (int i = 0; i < 8; ++i) {
        const int t   = w * 8 + i;                              // 0..63
        const int row = (t >> 1) * 16 + (t & 1) * 8 + (lane >> 3);
        stg[i] = *(const uint4*)(qw + (size_t)row * OUT_F + col0 + (lane & 7) * 4);
    }
    float    Scr[8][2];
    uint32_t Zqr[8][2];
    #pragma unroll
    for (int gp = 0; gp < 8; ++gp)
        #pragma unroll
        for (int nh = 0; nh < 2; ++nh) {
            Scr[gp][nh] = scales[(size_t)(g0 + gp) * OUT_F + col0 + nh * 16 + n];
            Zqr[gp][nh] = qz[(size_t)(g0 + gp) * ZCOLS + ((col0 + nh * 16 + n) >> 3)];
        }
    #pragma unroll
    for (int i = 0; i < 8; ++i)
        *(uint4*)&smem[(w * 8 + i) * 256 + lane * 4] = stg[i];
    __syncthreads();   // the one bulk drain

    // ---------------- phase 2: barrier-free K-loop ----------------
    // xf4 index: (mh*2+mt)*8192 + (kseg*32+kk)*64 + lane
    const int abase = mh * 16384 + kseg * 2048 + lane;
    // B word (kk, nh) at smem[bbase + kk*128 + nh*16]
    const int bbase = kseg * 4096 + quad * 32 + n;

    float4v acc[2][2];
    #pragma unroll
    for (int mt = 0; mt < 2; ++mt)
        #pragma unroll
        for (int nh = 0; nh < 2; ++nh)
            acc[mt][nh] = (float4v){0.f, 0.f, 0.f, 0.f};
    float4v accg[2][2];
    uint4    AR[3][2];
    uint32_t Bw[2][2];
    float4   XS[2];

    #pragma unroll
    for (int s = 0; s < 3; ++s) {
        AR[s][0] = xf4[abase + s * 64];
        AR[s][1] = xf4[abase + 8192 + s * 64];
    }
    #pragma unroll
    for (int b = 0; b < 2; ++b) {
        Bw[b][0] = smem[bbase + b * 128];
        Bw[b][1] = smem[bbase + b * 128 + 16];
    }

    #pragma unroll
    for (int kk = 0; kk < 32; ++kk) {
        const int s  = kk % 3;
        const int b  = kk & 1;
        const int ks = kk & 3;
        const int gp = kk >> 2;
        if (ks == 0) {
            #pragma unroll
            for (int mt = 0; mt < 2; ++mt) {
                XS[mt] = *(const float4*)(xsumT + (g0 + gp) * 64 +
                                          (mh * 2 + mt) * 16 + quad * 4);
                accg[mt][0] = (float4v){0.f, 0.f, 0.f, 0.f};
                accg[mt][1] = (float4v){0.f, 0.f, 0.f, 0.f};
            }
        }
        union { uint4 u; short8 s; } a0, a1;
        a0.u = AR[s][0];
        a1.u = AR[s][1];
        #pragma unroll
        for (int nh = 0; nh < 2; ++nh) {
            const uint32_t q  = Bw[b][nh];
            const uint32_t lo = q & 0x0F0F0F0Fu;
            const uint32_t hi = (q >> 4) & 0x0F0F0F0Fu;
            union { uint32_t u32[4]; short8 s8; } bf;
            #pragma unroll
            for (int i = 0; i < 4; ++i)
                bf.u32[i] = __builtin_amdgcn_perm(hi, lo, 0x0C040C00u + i * 0x00010001u)
                            | 0x43004300u;
            accg[0][nh] = __builtin_amdgcn_mfma_f32_16x16x32_bf16(a0.s, bf.s8,
                                                                  accg[0][nh], 0, 0, 0);
            accg[1][nh] = __builtin_amdgcn_mfma_f32_16x16x32_bf16(a1.s, bf.s8,
                                                                  accg[1][nh], 0, 0, 0);
        }
        if (kk + 3 < 32) {                       // A ring refill (L2-hot)
            AR[s][0] = xf4[abase + (kk + 3) * 64];
            AR[s][1] = xf4[abase + 8192 + (kk + 3) * 64];
        }
        if (kk + 2 < 32) {                       // B ring refill (LDS)
            Bw[b][0] = smem[bbase + (kk + 2) * 128];
            Bw[b][1] = smem[bbase + (kk + 2) * 128 + 16];
        }
        if (ks == 3) {                           // per-group fold
            #pragma unroll
            for (int nh = 0; nh < 2; ++nh) {
                const float zoff = (float)(((Zqr[gp][nh] >> ((n & 7) * 4)) & 0xFu) + 129u);
                const float scl  = Scr[gp][nh];
                #pragma unroll
                for (int mt = 0; mt < 2; ++mt) {
                    const float xr[4] = {XS[mt].x, XS[mt].y, XS[mt].z, XS[mt].w};
                    #pragma unroll
                    for (int r = 0; r < 4; ++r)
                        acc[mt][nh][r] = fmaf(scl, fmaf(-zoff, xr[r], accg[mt][nh][r]),
                                              acc[mt][nh][r]);
                }
            }
        }
    }

    // ---------------- epilogue: in-LDS split-K reduce + LoRA ----------------
    __syncthreads();   // all waves done reading B; safe to alias partials
    float* part = (float*)smem;        // 8 * 32 * PROW * 4 = 36864 B <= 64 KB
    {
        float* pb = part + (mh * 4 + kseg) * (32 * PROW);
        #pragma unroll
        for (int mt = 0; mt < 2; ++mt)
            #pragma unroll
            for (int nh = 0; nh < 2; ++nh)
                #pragma unroll
                for (int r = 0; r < 4; ++r)
                    pb[(mt * 16 + quad * 4 + r) * PROW + nh * 16 + n] = acc[mt][nh][r];
    }
    __syncthreads();
    {
        const int emh = tid >> 8;          // 0/1
        const int rem = tid & 255;
        const int tl  = rem >> 3;          // 0..31
        const int c4  = (rem & 7) * 4;     // 0,4,...,28
        const int t   = emh * 32 + tl;

        float4 sum = *(const float4*)&part[(emh * 4) * (32 * PROW) + tl * PROW + c4];
        #pragma unroll
        for (int ks = 1; ks < 4; ++ks) {
            const float4 p = *(const float4*)&part[(emh * 4 + ks) * (32 * PROW)
                                                   + tl * PROW + c4];
            sum.x += p.x; sum.y += p.y; sum.z += p.z; sum.w += p.w;
        }

        float m[16];
        #pragma unroll
        for (int j = 0; j < 16; ++j) m[j] = midT[j * TOKENS + t];
        float ls[4];
        #pragma unroll
        for (int c = 0; c < 4; ++c) {
            const float4* b4 = (const float4*)(loraB + (size_t)(col0 + c4 + c) * RANK);
            float a = 0.f;
            #pragma unroll
            for (int i = 0; i < 4; ++i) {
                float4 bv = b4[i];
                a += bv.x * m[i * 4 + 0] + bv.y * m[i * 4 + 1]
                   + bv.z * m[i * 4 + 2] + bv.w * m[i * 4 + 3];
            }
            ls[c] = a;
        }

        float4 o;
        o.x = sum.x + LORA_SCALE * ls[0];
        o.y = sum.y + LORA_SCALE * ls[1];
        o.z = sum.z + LORA_SCALE * ls[2];
        o.w = sum.w + LORA_SCALE * ls[3];
        *(float4*)(out + (size_t)t * OUT_F + col0 + c4) = o;
    }
}

// ---------------------------------------------------------------------------
extern "C" void kernel_launch(void* const* d_in, const int* in_sizes, int n_in,
                              void* d_out, int out_size, void* d_ws, size_t ws_size,
                              hipStream_t stream) {
    const float*    x      = (const float*)d_in[0];
    const uint32_t* qw     = (const uint32_t*)d_in[1];
    const uint32_t* qz     = (const uint32_t*)d_in[2];
    const float*    scales = (const float*)d_in[3];
    const float*    loraA  = (const float*)d_in[4];
    const float*    loraB  = (const float*)d_in[5];
    float* out = (float*)d_out;

    // ws layout: xf [4][128][64] uint4 (512 KB) | xsumT [32][64] | midT [16][64]
    uint4* xf4   = (uint4*)d_ws;
    float* xsumT = (float*)((char*)d_ws + (size_t)TOKENS * IN_F * 2);
    float* midT  = xsumT + NG * TOKENS;

    prep_kernel<<<TOKENS, 256, 0, stream>>>(x, loraA, xf4, xsumT, midT);
    main_kernel<<<OUT_F / 32, 512, 0, stream>>>(qw, qz, scales, xf4, xsumT,
                                                midT, loraB, out);
}

// Round 12
// 142.095 us; speedup vs baseline: 1.0044x; 1.0044x over previous
//
#include <hip/hip_runtime.h>
#include <stdint.h>

// Problem constants (fixed by setup_inputs)
#define TOKENS 64
#define IN_F   4096
#define OUT_F  11008
#define RANK   16
#define GS     128
#define NG     32
#define ZCOLS  (OUT_F / 8)
#define LORA_SCALE 2.0f
#define PROW 36               // padded LDS partial row stride (floats)

using short8  = __attribute__((ext_vector_type(8))) short;
using float4v = __attribute__((ext_vector_type(4))) float;

// async global->LDS, 16 B per lane; LDS dest = wave-uniform base + lane*16
static __device__ __forceinline__ void gld_lds16(const void* g, void* l) {
    __builtin_amdgcn_global_load_lds(
        (const __attribute__((address_space(1))) void*)g,
        (__attribute__((address_space(3))) void*)l, 16, 0, 0);
}

// round-to-nearest-even fp32 -> bf16 bits; also returns the rounded-back fp32
static __device__ inline uint16_t f2bf(float f, float* back) {
    uint32_t u = __float_as_uint(f);
    uint32_t r = (u + 0x7FFFu + ((u >> 16) & 1u)) >> 16;
    *back = __uint_as_float(r << 16);
    return (uint16_t)r;
}

// ---------------------------------------------------------------------------
// K1: per token t (64 blocks):
//   xf (MFMA-fragment order) = bf16(x)  — xf4[(mt*128 + kchunk)*64 + quad*16 + n]
//   xsumT[g][t] = sum over group g of bf16-rounded x   (GPTQ zero fold)
//   midT[j][t]  = sum_k x[t][k] * lora_A[j][k]         (fp32 LoRA mid)
// ---------------------------------------------------------------------------
__global__ __launch_bounds__(256) void prep_kernel(
        const float* __restrict__ x,
        const float* __restrict__ loraA,
        uint4* __restrict__ xf4,
        float* __restrict__ xsumT,
        float* __restrict__ midT) {
    __shared__ float redg[256];
    __shared__ float redm[4][16];
    const int t    = blockIdx.x;
    const int tid  = threadIdx.x;
    const int lane = tid & 63;
    const int wv   = tid >> 6;

    float4 xv[4];
    const float4* xp = (const float4*)(x + (size_t)t * IN_F + tid * 16);
    #pragma unroll
    for (int i = 0; i < 4; ++i) xv[i] = xp[i];

    union { uint16_t u[16]; uint4 q[2]; } ob;
    float s = 0.f;
    #pragma unroll
    for (int i = 0; i < 4; ++i) {
        float b;
        ob.u[i * 4 + 0] = f2bf(xv[i].x, &b); s += b;
        ob.u[i * 4 + 1] = f2bf(xv[i].y, &b); s += b;
        ob.u[i * 4 + 2] = f2bf(xv[i].z, &b); s += b;
        ob.u[i * 4 + 3] = f2bf(xv[i].w, &b); s += b;
    }
    // scatter into fragment order
    {
        const int mm = t >> 4, nn = t & 15;
        const int kchunk = tid >> 1;
        #pragma unroll
        for (int i = 0; i < 2; ++i) {
            const int qd = (tid * 2 + i) & 3;
            xf4[(size_t)((mm * 128 + kchunk) * 64 + qd * 16 + nn)] = ob.q[i];
        }
    }
    redg[tid] = s;

    // LoRA mid partials
    float pj[16];
    #pragma unroll
    for (int j = 0; j < 16; ++j) {
        const float4* ap = (const float4*)(loraA + (size_t)j * IN_F + tid * 16);
        float ps = 0.f;
        #pragma unroll
        for (int i = 0; i < 4; ++i) {
            float4 a = ap[i];
            ps += a.x * xv[i].x + a.y * xv[i].y + a.z * xv[i].z + a.w * xv[i].w;
        }
        pj[j] = ps;
    }
    #pragma unroll
    for (int j = 0; j < 16; ++j) {
        #pragma unroll
        for (int off = 32; off; off >>= 1) pj[j] += __shfl_down(pj[j], off);
    }
    if (lane == 0) {
        #pragma unroll
        for (int j = 0; j < 16; ++j) redm[wv][j] = pj[j];
    }
    __syncthreads();
    if (tid < NG) {
        float g = 0.f;
        #pragma unroll
        for (int i = 0; i < 8; ++i) g += redg[tid * 8 + i];
        xsumT[tid * TOKENS + t] = g;
    }
    if (tid < 16)
        midT[tid * TOKENS + t] = redm[0][tid] + redm[1][tid] + redm[2][tid] + redm[3][tid];
}

// ---------------------------------------------------------------------------
// K2: two-phase GPTQ-dequant GEMM + in-LDS split-K reduce + LoRA epilogue.
// Phase 1: B slice (512 rows x 32 cols = 64 KB) streamed to LDS via
//   global_load_lds width-16 (NO staging VGPRs — r11's spill source);
//   scales/qzeros prefetched to regs in the same vmcnt queue; one drain.
// Phase 2: barrier-free K-loop; vmcnt holds ONLY L2-hot loads (xf A-ring
//   depth 3, xsumT), B comes from LDS on lgkmcnt — latency classes separated.
// Block 512 = 8 waves = (mh 0/1) x (kseg 0..3); wave = 2 M-tiles x 32 cols
// x 8 groups (each dequanted word feeds 2 MFMAs). LDS partials (PROW=36)
// alias the dead B region. 3 barriers total. 2 blocks/CU co-resident.
// ---------------------------------------------------------------------------
__global__ __launch_bounds__(512, 4) void main_kernel(
        const uint32_t* __restrict__ qw,
        const uint32_t* __restrict__ qz,
        const float* __restrict__ scales,
        const uint4* __restrict__ xf4,
        const float* __restrict__ xsumT,
        const float* __restrict__ midT,
        const float* __restrict__ loraB,
        float* __restrict__ out) {
    __shared__ uint32_t smem[16384];   // 64 KB: B slice; later aliased by partials

    const int tid  = threadIdx.x;
    const int w    = tid >> 6;
    const int lane = tid & 63;
    const int n    = lane & 15;
    const int quad = lane >> 4;
    const int mh   = w >> 2;               // token half
    const int kseg = w & 3;                // 8-group K segment
    const int col0 = blockIdx.x * 32;
    const int g0   = kseg * 8;

    // ---------------- phase 1: bulk staging (no VGPR round-trip) ----------
    // wave w stages qw rows [w*64, w*64+64) of the block's 32-col slice:
    // 8 instrs, each 8 rows: lane -> (row = lane>>3, col4 = lane&7)
    #pragma unroll
    for (int i = 0; i < 8; ++i) {
        const int r0 = w * 64 + i * 8;
        gld_lds16(qw + (size_t)(r0 + (lane >> 3)) * OUT_F + col0 + (lane & 7) * 4,
                  &smem[r0 * 32]);
    }
    // per-wave scale/zero prefetch (drained by the same barrier)
    float    Scr[8][2];
    uint32_t Zqr[8][2];
    #pragma unroll
    for (int gp = 0; gp < 8; ++gp)
        #pragma unroll
        for (int nh = 0; nh < 2; ++nh) {
            Scr[gp][nh] = scales[(size_t)(g0 + gp) * OUT_F + col0 + nh * 16 + n];
            Zqr[gp][nh] = qz[(size_t)(g0 + gp) * ZCOLS + ((col0 + nh * 16 + n) >> 3)];
        }
    __syncthreads();   // the one bulk drain

    // ---------------- phase 2: barrier-free K-loop ----------------
    const int abase = mh * 16384 + kseg * 2048 + lane;   // xf4 units
    const int bbase = kseg * 4096 + quad * 32 + n;       // smem words

    float4v acc[2][2];
    #pragma unroll
    for (int mt = 0; mt < 2; ++mt)
        #pragma unroll
        for (int nh = 0; nh < 2; ++nh)
            acc[mt][nh] = (float4v){0.f, 0.f, 0.f, 0.f};
    float4v accg[2][2];
    uint4    AR[3][2];
    uint32_t Bw[2][2];
    float4   XS[2];

    #pragma unroll
    for (int s = 0; s < 3; ++s) {
        AR[s][0] = xf4[abase + s * 64];
        AR[s][1] = xf4[abase + 8192 + s * 64];
    }
    #pragma unroll
    for (int b = 0; b < 2; ++b) {
        Bw[b][0] = smem[bbase + b * 128];
        Bw[b][1] = smem[bbase + b * 128 + 16];
    }

    #pragma unroll
    for (int kk = 0; kk < 32; ++kk) {
        const int s  = kk % 3;
        const int b  = kk & 1;
        const int ks = kk & 3;
        const int gp = kk >> 2;
        if (ks == 0) {
            #pragma unroll
            for (int mt = 0; mt < 2; ++mt) {
                XS[mt] = *(const float4*)(xsumT + (g0 + gp) * 64 +
                                          (mh * 2 + mt) * 16 + quad * 4);
                accg[mt][0] = (float4v){0.f, 0.f, 0.f, 0.f};
                accg[mt][1] = (float4v){0.f, 0.f, 0.f, 0.f};
            }
        }
        union { uint4 u; short8 s; } a0, a1;
        a0.u = AR[s][0];
        a1.u = AR[s][1];
        #pragma unroll
        for (int nh = 0; nh < 2; ++nh) {
            const uint32_t q  = Bw[b][nh];
            const uint32_t lo = q & 0x0F0F0F0Fu;
            const uint32_t hi = (q >> 4) & 0x0F0F0F0Fu;
            union { uint32_t u32[4]; short8 s8; } bf;
            #pragma unroll
            for (int i = 0; i < 4; ++i)
                bf.u32[i] = __builtin_amdgcn_perm(hi, lo, 0x0C040C00u + i * 0x00010001u)
                            | 0x43004300u;
            accg[0][nh] = __builtin_amdgcn_mfma_f32_16x16x32_bf16(a0.s, bf.s8,
                                                                  accg[0][nh], 0, 0, 0);
            accg[1][nh] = __builtin_amdgcn_mfma_f32_16x16x32_bf16(a1.s, bf.s8,
                                                                  accg[1][nh], 0, 0, 0);
        }
        if (kk + 3 < 32) {                       // A ring refill (L2-hot, vmcnt)
            AR[s][0] = xf4[abase + (kk + 3) * 64];
            AR[s][1] = xf4[abase + 8192 + (kk + 3) * 64];
        }
        if (kk + 2 < 32) {                       // B ring refill (LDS, lgkmcnt)
            Bw[b][0] = smem[bbase + (kk + 2) * 128];
            Bw[b][1] = smem[bbase + (kk + 2) * 128 + 16];
        }
        if (ks == 3) {                           // per-group fold
            #pragma unroll
            for (int nh = 0; nh < 2; ++nh) {
                const float zoff = (float)(((Zqr[gp][nh] >> ((n & 7) * 4)) & 0xFu) + 129u);
                const float scl  = Scr[gp][nh];
                #pragma unroll
                for (int mt = 0; mt < 2; ++mt) {
                    const float xr[4] = {XS[mt].x, XS[mt].y, XS[mt].z, XS[mt].w};
                    #pragma unroll
                    for (int r = 0; r < 4; ++r)
                        acc[mt][nh][r] = fmaf(scl, fmaf(-zoff, xr[r], accg[mt][nh][r]),
                                              acc[mt][nh][r]);
                }
            }
        }
    }

    // ---------------- epilogue: in-LDS split-K reduce + LoRA ----------------
    __syncthreads();   // all waves done reading B; safe to alias partials
    float* part = (float*)smem;        // 8 * 32 * PROW * 4 = 36864 B <= 64 KB
    {
        float* pb = part + (mh * 4 + kseg) * (32 * PROW);
        #pragma unroll
        for (int mt = 0; mt < 2; ++mt)
            #pragma unroll
            for (int nh = 0; nh < 2; ++nh)
                #pragma unroll
                for (int r = 0; r < 4; ++r)
                    pb[(mt * 16 + quad * 4 + r) * PROW + nh * 16 + n] = acc[mt][nh][r];
    }
    __syncthreads();
    {
        const int emh = tid >> 8;          // 0/1
        const int rem = tid & 255;
        const int tl  = rem >> 3;          // 0..31
        const int c4  = (rem & 7) * 4;     // 0,4,...,28
        const int t   = emh * 32 + tl;

        float4 sum = *(const float4*)&part[(emh * 4) * (32 * PROW) + tl * PROW + c4];
        #pragma unroll
        for (int ks = 1; ks < 4; ++ks) {
            const float4 p = *(const float4*)&part[(emh * 4 + ks) * (32 * PROW)
                                                   + tl * PROW + c4];
            sum.x += p.x; sum.y += p.y; sum.z += p.z; sum.w += p.w;
        }

        float m[16];
        #pragma unroll
        for (int j = 0; j < 16; ++j) m[j] = midT[j * TOKENS + t];
        float ls[4];
        #pragma unroll
        for (int c = 0; c < 4; ++c) {
            const float4* b4 = (const float4*)(loraB + (size_t)(col0 + c4 + c) * RANK);
            float a = 0.f;
            #pragma unroll
            for (int i = 0; i < 4; ++i) {
                float4 bv = b4[i];
                a += bv.x * m[i * 4 + 0] + bv.y * m[i * 4 + 1]
                   + bv.z * m[i * 4 + 2] + bv.w * m[i * 4 + 3];
            }
            ls[c] = a;
        }

        float4 o;
        o.x = sum.x + LORA_SCALE * ls[0];
        o.y = sum.y + LORA_SCALE * ls[1];
        o.z = sum.z + LORA_SCALE * ls[2];
        o.w = sum.w + LORA_SCALE * ls[3];
        *(float4*)(out + (size_t)t * OUT_F + col0 + c4) = o;
    }
}

// ---------------------------------------------------------------------------
extern "C" void kernel_launch(void* const* d_in, const int* in_sizes, int n_in,
                              void* d_out, int out_size, void* d_ws, size_t ws_size,
                              hipStream_t stream) {
    const float*    x      = (const float*)d_in[0];
    const uint32_t* qw     = (const uint32_t*)d_in[1];
    const uint32_t* qz     = (const uint32_t*)d_in[2];
    const float*    scales = (const float*)d_in[3];
    const float*    loraA  = (const float*)d_in[4];
    const float*    loraB  = (const float*)d_in[5];
    float* out = (float*)d_out;

    // ws layout: xf [4][128][64] uint4 (512 KB) | xsumT [32][64] | midT [16][64]
    uint4* xf4   = (uint4*)d_ws;
    float* xsumT = (float*)((char*)d_ws + (size_t)TOKENS * IN_F * 2);
    float* midT  = xsumT + NG * TOKENS;

    prep_kernel<<<TOKENS, 256, 0, stream>>>(x, loraA, xf4, xsumT, midT);
    main_kernel<<<OUT_F / 32, 512, 0, stream>>>(qw, qz, scales, xf4, xsumT,
                                                midT, loraB, out);
}

// Round 13
// 140.626 us; speedup vs baseline: 1.0149x; 1.0104x over previous
//
#include <hip/hip_runtime.h>
#include <stdint.h>

// Problem constants (fixed by setup_inputs)
#define TOKENS 64
#define IN_F   4096
#define OUT_F  11008
#define RANK   16
#define GS     128
#define NG     32
#define ZCOLS  (OUT_F / 8)
#define LORA_SCALE 2.0f
#define PROW 36               // padded LDS partial row stride (floats)

using short8  = __attribute__((ext_vector_type(8))) short;
using float4v = __attribute__((ext_vector_type(4))) float;

// async global->LDS, 16 B per lane; LDS dest = wave-uniform base + lane*16
static __device__ __forceinline__ void gld_lds16(const void* g, void* l) {
    __builtin_amdgcn_global_load_lds(
        (const __attribute__((address_space(1))) void*)g,
        (__attribute__((address_space(3))) void*)l, 16, 0, 0);
}

// round-to-nearest-even fp32 -> bf16 bits; also returns the rounded-back fp32
static __device__ inline uint16_t f2bf(float f, float* back) {
    uint32_t u = __float_as_uint(f);
    uint32_t r = (u + 0x7FFFu + ((u >> 16) & 1u)) >> 16;
    *back = __uint_as_float(r << 16);
    return (uint16_t)r;
}

// ---------------------------------------------------------------------------
// K1: per token t (64 blocks):
//   xf (MFMA-fragment order) = bf16(x)  — xf4[(mt*128 + kchunk)*64 + quad*16 + n]
//   xsumT[g][t] = sum over group g of bf16-rounded x   (GPTQ zero fold)
//   midT[j][t]  = sum_k x[t][k] * lora_A[j][k]         (fp32 LoRA mid)
// ---------------------------------------------------------------------------
__global__ __launch_bounds__(256) void prep_kernel(
        const float* __restrict__ x,
        const float* __restrict__ loraA,
        uint4* __restrict__ xf4,
        float* __restrict__ xsumT,
        float* __restrict__ midT) {
    __shared__ float redg[256];
    __shared__ float redm[4][16];
    const int t    = blockIdx.x;
    const int tid  = threadIdx.x;
    const int lane = tid & 63;
    const int wv   = tid >> 6;

    float4 xv[4];
    const float4* xp = (const float4*)(x + (size_t)t * IN_F + tid * 16);
    #pragma unroll
    for (int i = 0; i < 4; ++i) xv[i] = xp[i];

    union { uint16_t u[16]; uint4 q[2]; } ob;
    float s = 0.f;
    #pragma unroll
    for (int i = 0; i < 4; ++i) {
        float b;
        ob.u[i * 4 + 0] = f2bf(xv[i].x, &b); s += b;
        ob.u[i * 4 + 1] = f2bf(xv[i].y, &b); s += b;
        ob.u[i * 4 + 2] = f2bf(xv[i].z, &b); s += b;
        ob.u[i * 4 + 3] = f2bf(xv[i].w, &b); s += b;
    }
    // scatter into fragment order
    {
        const int mm = t >> 4, nn = t & 15;
        const int kchunk = tid >> 1;
        #pragma unroll
        for (int i = 0; i < 2; ++i) {
            const int qd = (tid * 2 + i) & 3;
            xf4[(size_t)((mm * 128 + kchunk) * 64 + qd * 16 + nn)] = ob.q[i];
        }
    }
    redg[tid] = s;

    // LoRA mid partials
    float pj[16];
    #pragma unroll
    for (int j = 0; j < 16; ++j) {
        const float4* ap = (const float4*)(loraA + (size_t)j * IN_F + tid * 16);
        float ps = 0.f;
        #pragma unroll
        for (int i = 0; i < 4; ++i) {
            float4 a = ap[i];
            ps += a.x * xv[i].x + a.y * xv[i].y + a.z * xv[i].z + a.w * xv[i].w;
        }
        pj[j] = ps;
    }
    #pragma unroll
    for (int j = 0; j < 16; ++j) {
        #pragma unroll
        for (int off = 32; off; off >>= 1) pj[j] += __shfl_down(pj[j], off);
    }
    if (lane == 0) {
        #pragma unroll
        for (int j = 0; j < 16; ++j) redm[wv][j] = pj[j];
    }
    __syncthreads();
    if (tid < NG) {
        float g = 0.f;
        #pragma unroll
        for (int i = 0; i < 8; ++i) g += redg[tid * 8 + i];
        xsumT[tid * TOKENS + t] = g;
    }
    if (tid < 16)
        midT[tid * TOKENS + t] = redm[0][tid] + redm[1][tid] + redm[2][tid] + redm[3][tid];
}

// ---------------------------------------------------------------------------
// K2: two-phase GPTQ-dequant GEMM + in-LDS split-K reduce + LoRA epilogue.
// Phase 1: B slice (512 rows x 32 cols = 64 KB) streamed to LDS via
//   global_load_lds width-16 (no staging VGPRs); scales/qzeros prefetched to
//   regs in the same vmcnt queue; one drain.
// Phase 2: barrier-free K-loop; vmcnt holds ONLY L2-hot loads (xf A-ring
//   depth 3, xsumT), B comes from LDS on lgkmcnt — latency classes separated.
// Block 512 = 8 waves = (mh 0/1) x (kseg 0..3); wave = 2 M-tiles x 32 cols
// x 8 groups (each dequanted word feeds 2 MFMAs). LDS partials (PROW=36)
// alias the dead B region. 3 barriers total.
// __launch_bounds__(512, 3): reg cap ~170/lane. (512,4) capped at 128 unified
// -> 64 arch VGPR -> massive scratch spill (r11/r12: WRITE 80 MB). LDS (64 KB)
// already limits to 2 blocks/CU, so the tighter bound bought nothing.
// ---------------------------------------------------------------------------
__global__ __launch_bounds__(512, 3) void main_kernel(
        const uint32_t* __restrict__ qw,
        const uint32_t* __restrict__ qz,
        const float* __restrict__ scales,
        const uint4* __restrict__ xf4,
        const float* __restrict__ xsumT,
        const float* __restrict__ midT,
        const float* __restrict__ loraB,
        float* __restrict__ out) {
    __shared__ uint32_t smem[16384];   // 64 KB: B slice; later aliased by partials

    const int tid  = threadIdx.x;
    const int w    = tid >> 6;
    const int lane = tid & 63;
    const int n    = lane & 15;
    const int quad = lane >> 4;
    const int mh   = w >> 2;               // token half
    const int kseg = w & 3;                // 8-group K segment
    const int col0 = blockIdx.x * 32;
    const int g0   = kseg * 8;

    // ---------------- phase 1: bulk staging (no VGPR round-trip) ----------
    #pragma unroll
    for (int i = 0; i < 8; ++i) {
        const int r0 = w * 64 + i * 8;
        gld_lds16(qw + (size_t)(r0 + (lane >> 3)) * OUT_F + col0 + (lane & 7) * 4,
                  &smem[r0 * 32]);
    }
    // per-wave scale/zero prefetch (drained by the same barrier)
    float    Scr[8][2];
    uint32_t Zqr[8][2];
    #pragma unroll
    for (int gp = 0; gp < 8; ++gp)
        #pragma unroll
        for (int nh = 0; nh < 2; ++nh) {
            Scr[gp][nh] = scales[(size_t)(g0 + gp) * OUT_F + col0 + nh * 16 + n];
            Zqr[gp][nh] = qz[(size_t)(g0 + gp) * ZCOLS + ((col0 + nh * 16 + n) >> 3)];
        }
    __syncthreads();   // the one bulk drain

    // ---------------- phase 2: barrier-free K-loop ----------------
    const int abase = mh * 16384 + kseg * 2048 + lane;   // xf4 units
    const int bbase = kseg * 4096 + quad * 32 + n;       // smem words

    float4v acc[2][2];
    #pragma unroll
    for (int mt = 0; mt < 2; ++mt)
        #pragma unroll
        for (int nh = 0; nh < 2; ++nh)
            acc[mt][nh] = (float4v){0.f, 0.f, 0.f, 0.f};
    float4v accg[2][2];
    uint4    AR[3][2];
    uint32_t Bw[2][2];
    float4   XS[2];

    #pragma unroll
    for (int s = 0; s < 3; ++s) {
        AR[s][0] = xf4[abase + s * 64];
        AR[s][1] = xf4[abase + 8192 + s * 64];
    }
    #pragma unroll
    for (int b = 0; b < 2; ++b) {
        Bw[b][0] = smem[bbase + b * 128];
        Bw[b][1] = smem[bbase + b * 128 + 16];
    }

    #pragma unroll
    for (int kk = 0; kk < 32; ++kk) {
        const int s  = kk % 3;
        const int b  = kk & 1;
        const int ks = kk & 3;
        const int gp = kk >> 2;
        if (ks == 0) {
            #pragma unroll
            for (int mt = 0; mt < 2; ++mt) {
                XS[mt] = *(const float4*)(xsumT + (g0 + gp) * 64 +
                                          (mh * 2 + mt) * 16 + quad * 4);
                accg[mt][0] = (float4v){0.f, 0.f, 0.f, 0.f};
                accg[mt][1] = (float4v){0.f, 0.f, 0.f, 0.f};
            }
        }
        union { uint4 u; short8 s; } a0, a1;
        a0.u = AR[s][0];
        a1.u = AR[s][1];
        #pragma unroll
        for (int nh = 0; nh < 2; ++nh) {
            const uint32_t q  = Bw[b][nh];
            const uint32_t lo = q & 0x0F0F0F0Fu;
            const uint32_t hi = (q >> 4) & 0x0F0F0F0Fu;
            union { uint32_t u32[4]; short8 s8; } bf;
            #pragma unroll
            for (int i = 0; i < 4; ++i)
                bf.u32[i] = __builtin_amdgcn_perm(hi, lo, 0x0C040C00u + i * 0x00010001u)
                            | 0x43004300u;
            accg[0][nh] = __builtin_amdgcn_mfma_f32_16x16x32_bf16(a0.s, bf.s8,
                                                                  accg[0][nh], 0, 0, 0);
            accg[1][nh] = __builtin_amdgcn_mfma_f32_16x16x32_bf16(a1.s, bf.s8,
                                                                  accg[1][nh], 0, 0, 0);
        }
        if (kk + 3 < 32) {                       // A ring refill (L2-hot, vmcnt)
            AR[s][0] = xf4[abase + (kk + 3) * 64];
            AR[s][1] = xf4[abase + 8192 + (kk + 3) * 64];
        }
        if (kk + 2 < 32) {                       // B ring refill (LDS, lgkmcnt)
            Bw[b][0] = smem[bbase + (kk + 2) * 128];
            Bw[b][1] = smem[bbase + (kk + 2) * 128 + 16];
        }
        if (ks == 3) {                           // per-group fold
            #pragma unroll
            for (int nh = 0; nh < 2; ++nh) {
                const float zoff = (float)(((Zqr[gp][nh] >> ((n & 7) * 4)) & 0xFu) + 129u);
                const float scl  = Scr[gp][nh];
                #pragma unroll
                for (int mt = 0; mt < 2; ++mt) {
                    const float xr[4] = {XS[mt].x, XS[mt].y, XS[mt].z, XS[mt].w};
                    #pragma unroll
                    for (int r = 0; r < 4; ++r)
                        acc[mt][nh][r] = fmaf(scl, fmaf(-zoff, xr[r], accg[mt][nh][r]),
                                              acc[mt][nh][r]);
                }
            }
        }
    }

    // ---------------- epilogue: in-LDS split-K reduce + LoRA ----------------
    __syncthreads();   // all waves done reading B; safe to alias partials
    float* part = (float*)smem;        // 8 * 32 * PROW * 4 = 36864 B <= 64 KB
    {
        float* pb = part + (mh * 4 + kseg) * (32 * PROW);
        #pragma unroll
        for (int mt = 0; mt < 2; ++mt)
            #pragma unroll
            for (int nh = 0; nh < 2; ++nh)
                #pragma unroll
                for (int r = 0; r < 4; ++r)
                    pb[(mt * 16 + quad * 4 + r) * PROW + nh * 16 + n] = acc[mt][nh][r];
    }
    __syncthreads();
    {
        const int emh = tid >> 8;          // 0/1
        const int rem = tid & 255;
        const int tl  = rem >> 3;          // 0..31
        const int c4  = (rem & 7) * 4;     // 0,4,...,28
        const int t   = emh * 32 + tl;

        float4 sum = *(const float4*)&part[(emh * 4) * (32 * PROW) + tl * PROW + c4];
        #pragma unroll
        for (int ks = 1; ks < 4; ++ks) {
            const float4 p = *(const float4*)&part[(emh * 4 + ks) * (32 * PROW)
                                                   + tl * PROW + c4];
            sum.x += p.x; sum.y += p.y; sum.z += p.z; sum.w += p.w;
        }

        float m[16];
        #pragma unroll
        for (int j = 0; j < 16; ++j) m[j] = midT[j * TOKENS + t];
        float ls[4];
        #pragma unroll
        for (int c = 0; c < 4; ++c) {
            const float4* b4 = (const float4*)(loraB + (size_t)(col0 + c4 + c) * RANK);
            float a = 0.f;
            #pragma unroll
            for (int i = 0; i < 4; ++i) {
                float4 bv = b4[i];
                a += bv.x * m[i * 4 + 0] + bv.y * m[i * 4 + 1]
                   + bv.z * m[i * 4 + 2] + bv.w * m[i * 4 + 3];
            }
            ls[c] = a;
        }

        float4 o;
        o.x = sum.x + LORA_SCALE * ls[0];
        o.y = sum.y + LORA_SCALE * ls[1];
        o.z = sum.z + LORA_SCALE * ls[2];
        o.w = sum.w + LORA_SCALE * ls[3];
        *(float4*)(out + (size_t)t * OUT_F + col0 + c4) = o;
    }
}

// ---------------------------------------------------------------------------
extern "C" void kernel_launch(void* const* d_in, const int* in_sizes, int n_in,
                              void* d_out, int out_size, void* d_ws, size_t ws_size,
                              hipStream_t stream) {
    const float*    x      = (const float*)d_in[0];
    const uint32_t* qw     = (const uint32_t*)d_in[1];
    const uint32_t* qz     = (const uint32_t*)d_in[2];
    const float*    scales = (const float*)d_in[3];
    const float*    loraA  = (const float*)d_in[4];
    const float*    loraB  = (const float*)d_in[5];
    float* out = (float*)d_out;

    // ws layout: xf [4][128][64] uint4 (512 KB) | xsumT [32][64] | midT [16][64]
    uint4* xf4   = (uint4*)d_ws;
    float* xsumT = (float*)((char*)d_ws + (size_t)TOKENS * IN_F * 2);
    float* midT  = xsumT + NG * TOKENS;

    prep_kernel<<<TOKENS, 256, 0, stream>>>(x, loraA, xf4, xsumT, midT);
    main_kernel<<<OUT_F / 32, 512, 0, stream>>>(qw, qz, scales, xf4, xsumT,
                                                midT, loraB, out);
}